// Round 2
// baseline (3439.556 us; speedup 1.0000x reference)
//
#include <hip/hip_runtime.h>
#include <math.h>

// ---------------------------------------------------------------------------
// TDS decoder R6: 128 persistent blocks x 1024 threads.
//  R4 structure (LDS-flag gating, ONE-SHOT gh loads overlapping the gather)
//  + single-writer tagged 8B records replacing atomicAdd+counter protocol:
//   - each block stores its 41 fold-partials as {f32,tag} 8B atomics (one
//     relaxed store round, no RMW, no counter, no zero pass).
//   - wave0: fused poll+gather over 128 regions (tag==t validates data).
//   - wave1: polls entry-0 tags only -> go_lds (record visible => writer
//     passed barrier C => its gh stores are drained to MALL). GRU waves do
//     one-shot gh loads that overlap wave0's gather, exactly like R4.
//  2-deep buffers: records gate iteration entry, so no cross-iter overwrite.
// ---------------------------------------------------------------------------

#define NV      40
#define TENC    8192
#define MAXLEN  200
#define EOS_IDX 38
#define NB      128
#define NT      1024
#define NW      16
#define ROWS    64                    /* enc rows per block                 */
#define RPW     4                     /* enc rows per wave                  */
#define GHROWS  12                    /* W_hh rows per block (1536/128)     */
#define RSTRIDE 96                    /* floats per decide region (48x8B)   */
#define SCALE   0.04419417382415922f  /* 1/sqrt(512) */

/* ws layout (floats) */
#define WS_READY 0                            /* 128 x 8B                   */
#define WS_DEC   256                          /* 2 buf x 128 reg x 96       */
#define WS_HP    (WS_DEC + 2 * NB * RSTRIDE)  /* 24832: 2 x 96              */
#define WS_GH    (WS_HP + 2 * RSTRIDE)        /* 25024: 2 x 1536 (plain f32)*/
#define WS_GI    (WS_GH + 2 * 1536)           /* 28096: 40 x 1536           */

typedef unsigned long long u64;

__device__ __forceinline__ void st_tag(float* p, float v, int tag) {
  const u64 x = ((u64)(unsigned)tag << 32) | (u64)__float_as_uint(v);
  __hip_atomic_store((u64*)p, x, __ATOMIC_RELAXED, __HIP_MEMORY_SCOPE_AGENT);
}
__device__ __forceinline__ void st_tag_rel(float* p, float v, int tag) {
  const u64 x = ((u64)(unsigned)tag << 32) | (u64)__float_as_uint(v);
  __hip_atomic_store((u64*)p, x, __ATOMIC_RELEASE, __HIP_MEMORY_SCOPE_AGENT);
}
__device__ __forceinline__ u64 ld_tag(float* p) {
  return __hip_atomic_load((u64*)p, __ATOMIC_RELAXED, __HIP_MEMORY_SCOPE_AGENT);
}
#define TAGOF(x) ((int)(unsigned)((x) >> 32))
#define VALOF(x) __uint_as_float((unsigned)(x))

__device__ __forceinline__ float ld_af(float* p) {
  return __hip_atomic_load(p, __ATOMIC_RELAXED, __HIP_MEMORY_SCOPE_AGENT);
}
__device__ __forceinline__ void st_af(float* p, float v) {
  __hip_atomic_store(p, v, __ATOMIC_RELAXED, __HIP_MEMORY_SCOPE_AGENT);
}
__device__ __forceinline__ int ld_lds_acq(int* p) {
  return __hip_atomic_load(p, __ATOMIC_ACQUIRE, __HIP_MEMORY_SCOPE_WORKGROUP);
}
__device__ __forceinline__ void st_lds_rel(int* p, int v) {
  __hip_atomic_store(p, v, __ATOMIC_RELEASE, __HIP_MEMORY_SCOPE_WORKGROUP);
}

__device__ __forceinline__ float wred(float s) {
#pragma unroll
  for (int o = 32; o > 0; o >>= 1) s += __shfl_xor(s, o, 64);
  return s;
}
__device__ __forceinline__ float dot8(float4 a0, float4 a1, float4 b0,
                                      float4 b1) {
  return a0.x * b0.x + a0.y * b0.y + a0.z * b0.z + a0.w * b0.w +
         a1.x * b1.x + a1.y * b1.y + a1.z * b1.z + a1.w * b1.w;
}
__device__ __forceinline__ float wdot512(const float* __restrict__ a,
                                         const float* __restrict__ b) {
  const int l = threadIdx.x & 63;
  const float4 a0 = ((const float4*)a)[l];
  const float4 a1 = ((const float4*)a)[l + 64];
  const float4 b0 = ((const float4*)b)[l];
  const float4 b1 = ((const float4*)b)[l + 64];
  return wred(dot8(a0, a1, b0, b1));
}

__global__ void dec_init(int* wsi) {
  for (int k = threadIdx.x; k < WS_GH; k += NT) wsi[k] = 0;
}

__global__ void __launch_bounds__(NT, 4) dec_main(
    const float* __restrict__ enc, const float* __restrict__ hidden,
    const float* __restrict__ embed, const float* __restrict__ w_ih,
    const float* __restrict__ w_hh, const float* __restrict__ b_ih,
    const float* __restrict__ b_hh, const float* __restrict__ w_out,
    const float* __restrict__ b_out, float* __restrict__ o,
    float* __restrict__ ws) {
  const int b = blockIdx.x, tid = threadIdx.x;
  const int wave = tid >> 6, lane = tid & 63;
  const int r0 = b * ROWS;

  __shared__ __align__(16) float h_lds[512];
  __shared__ __align__(16) float whh_lds[GHROWS * 512];  /* 24 KB */
  __shared__ __align__(16) float whp_lds[512];
  __shared__ float pw_lds[NW * 48];
  __shared__ float sc_lds[1];
  __shared__ int go_lds;  /* t+1 when step-t gh rows are at the MALL */
  __shared__ int bf_lds;  /* (t<<6)|best */

  // ----------------- prologue: LDS staging -----------------
  if (tid < 512) h_lds[tid] = hidden[tid];
  {
    const float4* src = (const float4*)(w_hh + (size_t)b * GHROWS * 512);
    float4* dst = (float4*)whh_lds;
    for (int i = tid; i < GHROWS * 128; i += NT) dst[i] = src[i];
  }
  if (b < NV && tid < 128)
    ((float4*)whp_lds)[tid] =
        ((const float4*)(w_out + (size_t)b * 1024 + 512))[tid];
  if (tid == 0) { go_lds = 0; bf_lds = -1; }
  __syncthreads();

  // gi_all[v][j] = W_ih[j].embed[v] + b_ih[j]   (480 dots per block)
  for (int u = wave; u < 480; u += NW) {
    const int gl = b * 480 + u;
    const int v = gl / 1536, j = gl - v * 1536;
    const float d = wdot512(w_ih + (size_t)j * 512, embed + (size_t)v * 512);
    if (lane == 0) ws[WS_GI + (size_t)v * 1536 + j] = d + b_ih[j];
  }

  // M columns: Mv[r][lane] = W_out[lane,:512].V[row r]; lane40 = 1 (S col)
  const float* rowp = enc + (size_t)(r0 + wave * RPW) * 1024;
  float Mv[RPW];
#pragma unroll
  for (int r = 0; r < RPW; ++r) Mv[r] = (lane == 40) ? 1.0f : 0.0f;
  {
    float4 va[RPW], vb[RPW];
#pragma unroll
    for (int r = 0; r < RPW; ++r) {
      va[r] = ((const float4*)(rowp + r * 1024 + 512))[lane];
      vb[r] = ((const float4*)(rowp + r * 1024 + 512))[lane + 64];
    }
    for (int v = 0; v < NV; ++v) {
      const float* wp = w_out + (size_t)v * 1024;
      const float4 w0 = ((const float4*)wp)[lane];
      const float4 w1 = ((const float4*)wp)[lane + 64];
#pragma unroll
      for (int r = 0; r < RPW; ++r) {
        const float s = wred(dot8(va[r], vb[r], w0, w1));
        if (lane == v) Mv[r] = s;
      }
    }
  }
  // K rows into registers (re-uses the va/vb register budget)
  float4 ka[RPW], kb[RPW];
#pragma unroll
  for (int r = 0; r < RPW; ++r) {
    ka[r] = ((const float4*)(rowp + r * 1024))[lane];
    kb[r] = ((const float4*)(rowp + r * 1024))[lane + 64];
  }

  // biases + gh(h0) -> gh buffer 1 (read at t=0)
  float ghbias = 0.f, hpbias = (b < NV) ? b_out[b] : 0.f;
  if (wave >= 1 && wave <= GHROWS) {
    const int j = b * GHROWS + (wave - 1);
    ghbias = b_hh[j];
    const float4 hh0 = ((const float4*)h_lds)[lane];
    const float4 hh1 = ((const float4*)h_lds)[lane + 64];
    const float* wr = whh_lds + (wave - 1) * 512;
    const float d = wred(dot8(((const float4*)wr)[lane],
                              ((const float4*)wr)[lane + 64], hh0, hh1));
    if (lane == 0) st_af(&ws[WS_GH + 1536 + j], d + ghbias);
  }
  __syncthreads();  /* drain (vmcnt0) all prologue stores */
  if (tid == 0) st_tag_rel(&ws[WS_READY + 2 * b], 0.f, 1);  /* wbL2 + marker */

  // ----------------- main loop -----------------
  int eos_reg = -1;            /* block0/wave0/lane0 only */
  float pz[RPW];
#pragma unroll
  for (int r = 0; r < RPW; ++r) pz[r] = 0.f;
  float* attn = o + (size_t)MAXLEN * NV + 1;

  for (int t = 0; t <= MAXLEN; ++t) {
    if (wave == 0) {
      if (t == 0) {
        bool ok = false;
        for (;;) {
          if (!ok)
            ok = (TAGOF(ld_tag(&ws[WS_READY + 2 * lane])) == 1) &&
                 (TAGOF(ld_tag(&ws[WS_READY + 2 * (lane + 64)])) == 1);
          if (__ballot(!ok) == 0ull) break;
          __builtin_amdgcn_s_sleep(1);
        }
        if (lane == 0) st_lds_rel(&bf_lds, EOS_IDX);  /* (0<<6)|EOS */
      } else {
        // ---- fused poll+gather: data carries its own tag ----
        float* dbuf = ws + WS_DEC + (size_t)(t & 1) * (NB * RSTRIDE);
        float* hpb = ws + WS_HP + (size_t)(t & 1) * RSTRIDE;
        float cs = 0.f, hp = 0.f;
        for (;;) {
          int ok = 1;
          float c0 = 0, c1 = 0, c2 = 0, c3 = 0, hv = 0;
          if (lane < 41) {
#pragma unroll 8
            for (int q = 0; q < NB / 4; ++q) {
              const u64 a0 = ld_tag(&dbuf[(4 * q + 0) * RSTRIDE + 2 * lane]);
              const u64 a1 = ld_tag(&dbuf[(4 * q + 1) * RSTRIDE + 2 * lane]);
              const u64 a2 = ld_tag(&dbuf[(4 * q + 2) * RSTRIDE + 2 * lane]);
              const u64 a3 = ld_tag(&dbuf[(4 * q + 3) * RSTRIDE + 2 * lane]);
              c0 += VALOF(a0); c1 += VALOF(a1);
              c2 += VALOF(a2); c3 += VALOF(a3);
              ok &= (TAGOF(a0) == t) & (TAGOF(a1) == t) & (TAGOF(a2) == t) &
                    (TAGOF(a3) == t);
            }
            if (lane < NV) {
              const u64 ah = ld_tag(&hpb[2 * lane]);
              hv = VALOF(ah);
              ok &= (TAGOF(ah) == t);
            }
          }
          if (__ballot(!ok) == 0ull) {
            cs = (c0 + c1) + (c2 + c3);
            hp = hv;
            break;
          }
          __builtin_amdgcn_s_sleep(1);
        }
        const float S = __shfl(cs, NV, 64);
        const float ov = cs * (1.0f / S) + hp;
        unsigned long long key = 0ull;
        if (lane < NV) {
          unsigned u_ = __float_as_uint(ov);
          u_ = (u_ & 0x80000000u) ? ~u_ : (u_ | 0x80000000u);
          key = ((unsigned long long)u_ << 32) | (unsigned)(~lane);
        }
#pragma unroll
        for (int m = 32; m > 0; m >>= 1) {
          const unsigned long long k2 = __shfl_xor(key, m, 64);
          if (k2 > key) key = k2;
        }
        const int best = (int)(~(unsigned)key);
        if (b == 0 && lane < NV) o[(size_t)(t - 1) * NV + lane] = ov;
        if (lane == 0) {
          sc_lds[0] = S;
          if (b == 0) {
            if (best == EOS_IDX && eos_reg < 0) eos_reg = t - 1;
            if (t == MAXLEN)
              o[(size_t)MAXLEN * NV] =
                  (eos_reg < 0) ? (float)MAXLEN : (float)eos_reg;
          }
          st_lds_rel(&bf_lds, (t << 6) | best);
        }
      }
    } else if (wave == 1) {
      // ---- go detector: entry-0 tags only -> go_lds (cheap, parallel) ----
      if (t == 0) {
        bool ok = false;
        for (;;) {
          if (!ok)
            ok = (TAGOF(ld_tag(&ws[WS_READY + 2 * lane])) == 1) &&
                 (TAGOF(ld_tag(&ws[WS_READY + 2 * (lane + 64)])) == 1);
          if (__ballot(!ok) == 0ull) break;
          __builtin_amdgcn_s_sleep(1);
        }
      } else {
        float* dbuf = ws + WS_DEC + (size_t)(t & 1) * (NB * RSTRIDE);
        bool ok = false;
        for (;;) {
          if (!ok)
            ok = (TAGOF(ld_tag(&dbuf[lane * RSTRIDE])) == t) &&
                 (TAGOF(ld_tag(&dbuf[(lane + 64) * RSTRIDE])) == t);
          if (__ballot(!ok) == 0ull) break;
          __builtin_amdgcn_s_sleep(1);
        }
      }
      if (lane == 0) st_lds_rel(&go_lds, t + 1);
    } else if (wave >= 8 && t < MAXLEN) {
      // ---- GRU waves: wait LDS flag, then ONE-SHOT gh loads (overlap) ----
      const int j = tid - 512;
      while (ld_lds_acq(&go_lds) < t + 1) __builtin_amdgcn_s_sleep(1);
      float* ghs = ws + WS_GH + (size_t)((t + 1) & 1) * 1536;
      const float ghr = ld_af(&ghs[j]);
      const float ghz = ld_af(&ghs[j + 512]);
      const float ghn = ld_af(&ghs[j + 1024]);
      int bf;
      while (((bf = ld_lds_acq(&bf_lds)) >> 6) < t) __builtin_amdgcn_s_sleep(1);
      const float* gi = ws + WS_GI + (size_t)(bf & 63) * 1536;
      const float gir = gi[j], giz = gi[j + 512], gin = gi[j + 1024];
      const float r_ = 1.0f / (1.0f + expf(-(gir + ghr)));
      const float z_ = 1.0f / (1.0f + expf(-(giz + ghz)));
      const float n_ = tanhf(gin + r_ * ghn);
      h_lds[j] = (1.0f - z_) * n_ + z_ * h_lds[j];
    }
    __syncthreads();  // barrier A: h_t, sc_lds ready

    // store previous step's normalized attention weights (p in regs)
    if (t > 0 && lane < RPW) {
      float pv = pz[0];
#pragma unroll
      for (int r = 1; r < RPW; ++r) pv = (lane == r) ? pz[r] : pv;
      attn[(size_t)(t - 1) * TENC + r0 + wave * RPW + lane] =
          pv * (1.0f / sc_lds[0]);
    }
    if (t == MAXLEN) break;

    // ---- dots: K in registers, h and aux rows in LDS ----
    {
      const float4 hh0 = ((const float4*)h_lds)[lane];
      const float4 hh1 = ((const float4*)h_lds)[lane + 64];
      float dsum[RPW];
#pragma unroll
      for (int r = 0; r < RPW; ++r) dsum[r] = dot8(ka[r], kb[r], hh0, hh1);
#pragma unroll
      for (int r = 0; r < RPW; ++r) dsum[r] = wred(dsum[r]);
      float fold = 0.f;
#pragma unroll
      for (int r = 0; r < RPW; ++r) {
        const float p = expf(dsum[r] * SCALE);
        pz[r] = p;
        fold += p * Mv[r];
      }
      if (lane < 41) pw_lds[wave * 48 + lane] = fold;
      if (wave >= 1 && wave <= GHROWS) {  // gh row for step t+1
        const float* wr = whh_lds + (wave - 1) * 512;
        const float d = wred(dot8(((const float4*)wr)[lane],
                                  ((const float4*)wr)[lane + 64], hh0, hh1));
        if (lane == 0)
          st_af(&ws[WS_GH + (size_t)(t & 1) * 1536 + b * GHROWS + (wave - 1)],
                d + ghbias);
      } else if (wave == 13 && b < NV) {  // hp row -> tag t+1
        const float d = wred(dot8(((const float4*)whp_lds)[lane],
                                  ((const float4*)whp_lds)[lane + 64], hh0,
                                  hh1));
        if (lane == 0)
          st_tag(&ws[WS_HP + (size_t)((t + 1) & 1) * RSTRIDE + 2 * b],
                 d + hpbias, t + 1);
      }
    }
    __syncthreads();  // barrier C: pw complete, gh/hp stores drained

    // ---- wave0: reduce 16 wave-partials, push tagged record ----
    if (wave == 0 && lane < 41) {
      float s = 0.f;
#pragma unroll
      for (int w2 = 0; w2 < NW; ++w2) s += pw_lds[w2 * 48 + lane];
      st_tag(&ws[WS_DEC + (size_t)((t + 1) & 1) * (NB * RSTRIDE) +
                 b * RSTRIDE + 2 * lane],
             s, t + 1);
    }
  }
}

extern "C" void kernel_launch(void* const* d_in, const int* in_sizes, int n_in,
                              void* d_out, int out_size, void* d_ws,
                              size_t ws_size, hipStream_t stream) {
  const float* enc    = (const float*)d_in[0];
  const float* hidden = (const float*)d_in[1];
  const float* embed  = (const float*)d_in[2];
  const float* w_ih   = (const float*)d_in[3];
  const float* w_hh   = (const float*)d_in[4];
  const float* b_ih   = (const float*)d_in[5];
  const float* b_hh   = (const float*)d_in[6];
  const float* w_out  = (const float*)d_in[7];
  const float* b_out  = (const float*)d_in[8];
  float* out = (float*)d_out;
  float* ws  = (float*)d_ws;

  dec_init<<<dim3(1), dim3(NT), 0, stream>>>((int*)d_ws);
  dec_main<<<dim3(NB), dim3(NT), 0, stream>>>(enc, hidden, embed, w_ih, w_hh,
                                              b_ih, b_hh, w_out, b_out, out,
                                              ws);
}

// Round 3
// 1651.174 us; speedup vs baseline: 2.0831x; 2.0831x over previous
//
#include <hip/hip_runtime.h>
#include <math.h>

// ---------------------------------------------------------------------------
// TDS decoder R7: R4 (verified 1507us) + deferred-release optimization.
//  - Per-step push: wave0 reduces 16 wave-partials in LDS and issues 41
//    atomicAdds (as R4), but the release fetch_add is DEFERRED into the
//    first iteration of the NEXT decide's counter poll: its vmcnt(0) ack
//    wait (~0.3us) then overlaps the first poll round trip instead of
//    serially preceding counter visibility. Ordering unchanged: release is
//    still after barrier C (all waves' gh/hp/zero stores drained) and after
//    this wave's data adds in program order.
//  - hp load issued before the 64 gather-chain loads (in-order vmcnt =>
//    hp result available after one latency, not after 64 returns).
//  - Everything else byte-identical to R4: 256 blocks x 1024 threads,
//    K/M/aux rows in registers, LDS go/best flags, 3-slot rotation,
//    sticky counter poll, one pipelined gather pass.
// ---------------------------------------------------------------------------

#define NV      40
#define TENC    8192
#define MAXLEN  200
#define EOS_IDX 38
#define NB      256
#define NT      1024
#define NW      16
#define ROWS    32
#define NG      64                    /* groups of NB/NG=4 blocks           */
#define GSTRIDE 96                    /* floats per group region            */
#define GCNT    64                    /* counter col (own cacheline)        */
#define HPOFF   (NG * GSTRIDE)        /* 6144: hp line within slot          */
#define SLOT    (HPOFF + 64)          /* 6208 floats per rotation slot      */
#define SCALE   0.04419417382415922f  /* 1/sqrt(512) */

#define WS_ACC  128                   /* float[3][SLOT]                     */
#define WS_GH   (WS_ACC + 3 * SLOT)   /* 18752: float[3][1536]              */
#define WS_GI   (WS_GH + 3 * 1536)    /* 23360: float[40*1536]              */

__device__ __forceinline__ int ld_ai(int* p) {
  return __hip_atomic_load(p, __ATOMIC_RELAXED, __HIP_MEMORY_SCOPE_AGENT);
}
__device__ __forceinline__ float ld_af(float* p) {
  return __hip_atomic_load(p, __ATOMIC_RELAXED, __HIP_MEMORY_SCOPE_AGENT);
}
__device__ __forceinline__ void st_af(float* p, float v) {
  __hip_atomic_store(p, v, __ATOMIC_RELAXED, __HIP_MEMORY_SCOPE_AGENT);
}
__device__ __forceinline__ void st_ai(int* p, int v) {
  __hip_atomic_store(p, v, __ATOMIC_RELAXED, __HIP_MEMORY_SCOPE_AGENT);
}
__device__ __forceinline__ int ld_lds_acq(int* p) {
  return __hip_atomic_load(p, __ATOMIC_ACQUIRE, __HIP_MEMORY_SCOPE_WORKGROUP);
}
__device__ __forceinline__ void st_lds_rel(int* p, int v) {
  __hip_atomic_store(p, v, __ATOMIC_RELEASE, __HIP_MEMORY_SCOPE_WORKGROUP);
}

__device__ __forceinline__ float wred(float s) {
#pragma unroll
  for (int o = 32; o > 0; o >>= 1) s += __shfl_xor(s, o, 64);
  return s;
}
__device__ __forceinline__ float dot8(float4 a0, float4 a1, float4 b0,
                                      float4 b1) {
  return a0.x * b0.x + a0.y * b0.y + a0.z * b0.z + a0.w * b0.w +
         a1.x * b1.x + a1.y * b1.y + a1.z * b1.z + a1.w * b1.w;
}
__device__ __forceinline__ float wdot512(const float* __restrict__ a,
                                         const float* __restrict__ b) {
  const int l = threadIdx.x & 63;
  const float4 a0 = ((const float4*)a)[l];
  const float4 a1 = ((const float4*)a)[l + 64];
  const float4 b0 = ((const float4*)b)[l];
  const float4 b1 = ((const float4*)b)[l + 64];
  return wred(dot8(a0, a1, b0, b1));
}

__global__ void dec_init(int* wsi) {
  for (int k = threadIdx.x; k < WS_GH; k += NT) wsi[k] = 0;
}

__global__ void __launch_bounds__(NT, 4) dec_main(
    const float* __restrict__ enc, const float* __restrict__ hidden,
    const float* __restrict__ embed, const float* __restrict__ w_ih,
    const float* __restrict__ w_hh, const float* __restrict__ b_ih,
    const float* __restrict__ b_hh, const float* __restrict__ w_out,
    const float* __restrict__ b_out, float* __restrict__ o,
    float* __restrict__ ws) {
  const int b = blockIdx.x, tid = threadIdx.x;
  const int wave = tid >> 6, lane = tid & 63;
  const int g = b & (NG - 1);
  const int r0 = b * ROWS;

  __shared__ __align__(16) float h_lds[512];
  __shared__ float pw_lds[NW * 48];
  __shared__ float sc_lds[1];
  __shared__ int go_lds;  // t+1 when step-t inputs are at the MALL
  __shared__ int bf_lds;  // (t<<6)|best

  // ----------------- prologue -----------------
  if (tid < 512) h_lds[tid] = hidden[tid];
  if (tid == 0) { go_lds = 0; bf_lds = -1; }

  // gi_all[v][j] = W_ih[j].embed[v] + b_ih[j]  (240 dots per block)
  for (int u = wave; u < 240; u += NW) {
    const int gl = b * 240 + u;
    const int v = gl / 1536, j = gl - v * 1536;
    const float d = wdot512(w_ih + (size_t)j * 512, embed + (size_t)v * 512);
    if (lane == 0) ws[WS_GI + (size_t)v * 1536 + j] = d + b_ih[j];
  }
  // gh(h0) -> slot 2  (waves 0-5, one row each)
  for (int jr = wave; jr < 6; jr += NW) {
    const int j = b * 6 + jr;
    const float d = wdot512(w_hh + (size_t)j * 512, hidden);
    if (lane == 0) st_af(&ws[WS_GH + 2 * 1536 + j], d + b_hh[j]);
  }
  __syncthreads();  // drain stores
  if (tid == 0)
    __hip_atomic_fetch_add((int*)(ws + WS_ACC + 2 * SLOT + g * GSTRIDE + GCNT),
                           1, __ATOMIC_RELEASE, __HIP_MEMORY_SCOPE_AGENT);

  // --- register-resident operands ---
  const float* k0p = enc + (size_t)(r0 + 2 * wave) * 1024;
  const float4 k0a = ((const float4*)k0p)[lane];
  const float4 k0b = ((const float4*)k0p)[lane + 64];
  const float4 k1a = ((const float4*)(k0p + 1024))[lane];
  const float4 k1b = ((const float4*)(k0p + 1024))[lane + 64];

  // M columns: Mr0/Mr1 = W_out[lane,:512].V[row0/1]; lane40 = 1 (S column)
  float Mr0 = (lane == 40) ? 1.0f : 0.0f, Mr1 = Mr0;
  {
    const float* v0p = k0p + 512;
    const float4 va0 = ((const float4*)v0p)[lane];
    const float4 va1 = ((const float4*)v0p)[lane + 64];
    const float4 vb0 = ((const float4*)(v0p + 1024))[lane];
    const float4 vb1 = ((const float4*)(v0p + 1024))[lane + 64];
    for (int v = 0; v < NV; ++v) {
      const float* wp = w_out + (size_t)v * 1024;
      const float4 w0 = ((const float4*)wp)[lane];
      const float4 w1 = ((const float4*)wp)[lane + 64];
      const float sa = wred(dot8(va0, va1, w0, w1));
      const float sb = wred(dot8(vb0, vb1, w0, w1));
      if (lane == v) { Mr0 = sa; Mr1 = sb; }
    }
  }
  // aux row: waves 1-6 -> W_hh row b*6+wave-1; wave 7 (b in 1..40) -> W_out hp
  float4 xa0 = {0, 0, 0, 0}, xa1 = {0, 0, 0, 0};
  float xb = 0.0f;
  if (wave >= 1 && wave <= 6) {
    const int j = b * 6 + (wave - 1);
    const float* wp = w_hh + (size_t)j * 512;
    xa0 = ((const float4*)wp)[lane];
    xa1 = ((const float4*)wp)[lane + 64];
    xb = b_hh[j];
  } else if (wave == 7 && b >= 1 && b <= NV) {
    const float* wp = w_out + (size_t)(b - 1) * 1024 + 512;
    xa0 = ((const float4*)wp)[lane];
    xa1 = ((const float4*)wp)[lane + 64];
    xb = b_out[b - 1];
  }

  // ----------------- main loop -----------------
  int eos_reg = -1;              // block0/wave0/lane0 only
  float p0 = 0.0f, p1 = 0.0f;    // this wave's attention weights (unnorm.)
  float* attn = o + (size_t)MAXLEN * NV + 1;

  for (int t = 0; t <= MAXLEN; ++t) {
    if (wave == 0) {
      float* accs = ws + WS_ACC + ((t + 2) % 3) * SLOT;
      {  // poll all NG counters (sticky per lane) + deferred release.
        // Our step-(t-1) data adds were issued before this loop; vmcnt is
        // in-order, so by the time the first poll round's loads are waited
        // on, the adds are acked -> the release's vmcnt(0) is ~free and its
        // travel overlaps the poll instead of preceding it.
        int* cp = (int*)(accs + lane * GSTRIDE + GCNT);
        bool ok = false;
        bool rel = (t == 0);  // t==0: prologue already released
        for (;;) {
          if (!ok) ok = (ld_ai(cp) >= NB / NG);
          if (!rel) {
            if (lane == 0)
              __hip_atomic_fetch_add((int*)(accs + g * GSTRIDE + GCNT), 1,
                                     __ATOMIC_RELEASE,
                                     __HIP_MEMORY_SCOPE_AGENT);
            rel = true;
          }
          if (__ballot(!ok) == 0ull) break;
          __builtin_amdgcn_s_sleep(1);
        }
      }
      if (lane == 0) st_lds_rel(&go_lds, t + 1);  // GRU waves may start gh
      if (t > 0) {
        // hp first (in-order vmcnt: result lands after one latency)
        const float hp = (lane < NV) ? ld_af(&accs[HPOFF + lane]) : 0.0f;
        // gather 64 group partials (4 chains, all loads pipelined)
        float c0 = 0, c1 = 0, c2 = 0, c3 = 0;
#pragma unroll
        for (int q = 0; q < NG / 4; ++q) {
          c0 += ld_af(&accs[(4 * q + 0) * GSTRIDE + lane]);
          c1 += ld_af(&accs[(4 * q + 1) * GSTRIDE + lane]);
          c2 += ld_af(&accs[(4 * q + 2) * GSTRIDE + lane]);
          c3 += ld_af(&accs[(4 * q + 3) * GSTRIDE + lane]);
        }
        const float cs = (c0 + c1) + (c2 + c3);
        const float S = __shfl(cs, NV, 64);
        const float ov = cs * (1.0f / S) + hp;
        unsigned long long key = 0ull;
        if (lane < NV) {
          unsigned u = __float_as_uint(ov);
          u = (u & 0x80000000u) ? ~u : (u | 0x80000000u);
          key = ((unsigned long long)u << 32) | (unsigned)(~lane);
        }
#pragma unroll
        for (int m = 32; m > 0; m >>= 1) {
          const unsigned long long k2 = __shfl_xor(key, m, 64);
          if (k2 > key) key = k2;
        }
        const int best = (int)(~(unsigned)key);
        if (b == 0 && lane < NV) o[(size_t)(t - 1) * NV + lane] = ov;
        if (lane == 0) {
          sc_lds[0] = S;
          if (b == 0) {
            if (best == EOS_IDX && eos_reg < 0) eos_reg = t - 1;
            if (t == MAXLEN)
              o[(size_t)MAXLEN * NV] =
                  (eos_reg < 0) ? (float)MAXLEN : (float)eos_reg;
          }
          st_lds_rel(&bf_lds, (t << 6) | best);
        }
      } else if (lane == 0) {
        st_lds_rel(&bf_lds, EOS_IDX);  // (0<<6)|EOS
      }
    } else if (wave >= 8 && t < MAXLEN) {
      // ---- GRU waves: gh loads overlap wave0's decide ----
      const int j = tid - 512;
      while (ld_lds_acq(&go_lds) < t + 1) __builtin_amdgcn_s_sleep(1);
      float* ghs = ws + WS_GH + ((t + 2) % 3) * 1536;
      const float ghr = ld_af(&ghs[j]);
      const float ghz = ld_af(&ghs[j + 512]);
      const float ghn = ld_af(&ghs[j + 1024]);
      int bf;
      while (((bf = ld_lds_acq(&bf_lds)) >> 6) < t) __builtin_amdgcn_s_sleep(1);
      const float* gi = ws + WS_GI + (size_t)(bf & 63) * 1536;
      const float gir = gi[j], giz = gi[j + 512], gin = gi[j + 1024];
      const float r = 1.0f / (1.0f + expf(-(gir + ghr)));
      const float z = 1.0f / (1.0f + expf(-(giz + ghz)));
      const float n = tanhf(gin + r * ghn);
      h_lds[j] = (1.0f - z) * n + z * h_lds[j];
    }
    __syncthreads();  // barrier A: h_t, sc_lds ready

    // store previous step's normalized attention weights (p in regs)
    if (t > 0 && lane < 2)
      attn[(size_t)(t - 1) * TENC + r0 + 2 * wave + lane] =
          (lane ? p1 : p0) * (1.0f / sc_lds[0]);
    if (t == MAXLEN) break;

    // ---- dots: all operands in registers / LDS ----
    {
      const float4 hh0 = ((const float4*)h_lds)[lane];
      const float4 hh1 = ((const float4*)h_lds)[lane + 64];
      const float d0 = wred(dot8(k0a, k0b, hh0, hh1));
      const float d1 = wred(dot8(k1a, k1b, hh0, hh1));
      p0 = expf(d0 * SCALE);
      p1 = expf(d1 * SCALE);
      if (lane < 41) pw_lds[wave * 48 + lane] = p0 * Mr0 + p1 * Mr1;
      if (wave >= 1 && wave <= 6) {  // gh_t row for step t+1
        const float d = wred(dot8(xa0, xa1, hh0, hh1));
        if (lane == 0)
          st_af(&ws[WS_GH + (t % 3) * 1536 + b * 6 + (wave - 1)], d + xb);
      } else if (wave == 7 && b >= 1 && b <= NV) {  // hp row
        const float d = wred(dot8(xa0, xa1, hh0, hh1));
        if (lane == 0)
          st_af(&ws[WS_ACC + (t % 3) * SLOT + HPOFF + (b - 1)], d + xb);
      } else if (wave == 15 && b < NG) {  // zero slot (t+1)%3 group b
        float* nx = ws + WS_ACC + ((t + 1) % 3) * SLOT + b * GSTRIDE;
        if (lane < 41) st_af(&nx[lane], 0.0f);
        else if (lane == 41) st_ai((int*)&nx[GCNT], 0);
      }
    }
    __syncthreads();  // barrier C: pw complete, all stores drained

    // ---- wave0: reduce 16 wave-partials, push data adds (release deferred
    //      into the next decide's poll loop) ----
    if (wave == 0 && lane < 41) {
      float* accsT = ws + WS_ACC + (t % 3) * SLOT;
      float s = 0.0f;
#pragma unroll
      for (int w2 = 0; w2 < NW; ++w2) s += pw_lds[w2 * 48 + lane];
      atomicAdd(&accsT[g * GSTRIDE + lane], s);
    }
  }
}

extern "C" void kernel_launch(void* const* d_in, const int* in_sizes, int n_in,
                              void* d_out, int out_size, void* d_ws,
                              size_t ws_size, hipStream_t stream) {
  const float* enc    = (const float*)d_in[0];
  const float* hidden = (const float*)d_in[1];
  const float* embed  = (const float*)d_in[2];
  const float* w_ih   = (const float*)d_in[3];
  const float* w_hh   = (const float*)d_in[4];
  const float* b_ih   = (const float*)d_in[5];
  const float* b_hh   = (const float*)d_in[6];
  const float* w_out  = (const float*)d_in[7];
  const float* b_out  = (const float*)d_in[8];
  float* out = (float*)d_out;
  float* ws  = (float*)d_ws;

  dec_init<<<dim3(1), dim3(NT), 0, stream>>>((int*)d_ws);
  dec_main<<<dim3(NB), dim3(NT), 0, stream>>>(enc, hidden, embed, w_ih, w_hh,
                                              b_ih, b_hh, w_out, b_out, out,
                                              ws);
}